// Round 2
// 168.638 us; speedup vs baseline: 1.0116x; 1.0116x over previous
//
#include <hip/hip_runtime.h>
#include <stdint.h>

// Problem constants (B=16, A=3, H=W=76, ATTR=5+80=85)
// Input:  fp32, shape (16, 255, 76, 76)   = 23,566,080 floats (94.3 MB)
// Output: fp32, shape (16, 3, 76, 76, 85) = 23,566,080 floats (94.3 MB)
#define NB       16
#define NA       3
#define HH_      76
#define WW_      76
#define S_TOT    (HH_ * WW_)          // 5776 spatial positions
#define ATTR     85
#define TILE_S   152                  // spatial positions per block (2 image rows)
#define TILES    (S_TOT / TILE_S)     // 38
#define NTHREADS 512
#define QUADS    22                   // ceil(85/4) attrib quads per spatial pos
#define UNITS1   (QUADS * TILE_S)     // 3344 phase-1 units (one s x 4 attribs)
#define UNITS2   (TILE_S * ATTR / 4)  // 3230 phase-2 float4 granules
#define NB1      7                    // ceil(UNITS1 / NTHREADS)
#define NB2      7                    // ceil(UNITS2 / NTHREADS)
#define LOG2E    1.44269504088896340f

typedef __attribute__((ext_vector_type(4))) float float4v;

__device__ __forceinline__ float fast_sigmoid(float x) {
    // 1 / (1 + e^-x) = rcp(1 + exp2(-x*log2e)); x ~ N(0,1), |x| <= ~6, finite
    float e = __builtin_amdgcn_exp2f(x * (-LOG2E));
    return __builtin_amdgcn_rcpf(1.0f + e);
}

__global__ __launch_bounds__(NTHREADS)
void yolo_layer_kernel(const float* __restrict__ in,
                       float* __restrict__ out) {
    // LDS holds the fp32 output tile verbatim: [TILE_S][ATTR], unpadded.
    // 152*85*4 = 51,680 B -> 3 blocks/CU (24 waves, same occupancy as before).
    __shared__ __attribute__((aligned(16))) float lds[TILE_S * ATTR];

    const int tid  = threadIdx.x;
    const int tile = blockIdx.x;          // 0..37  (spatial tile)
    const int BA   = blockIdx.y;          // 0..47  (b*3 + a)
    const int a    = BA % NA;
    const int s0   = tile * TILE_S;

    // anchor constants (faithful to reference's off-by-one anchor_h indexing:
    // ANCHOR_W = [10,13,16], ANCHOR_H = [13,16,30])
    const float aw = (a == 0) ? 10.0f : (a == 1) ? 13.0f : 16.0f;
    const float ah = (a == 0) ? 13.0f : (a == 1) ? 16.0f : 30.0f;
    const float cw = aw * (1.0f / 608.0f);
    const float ch = ah * (1.0f / 608.0f);

    const float* inb = in + (size_t)BA * (ATTR * S_TOT) + s0;

    // ---------- Phase 1a: issue ALL loads back-to-back (28 b32 loads/thread) ----
    // Unit u = g*TILE_S + s : one spatial position s, attribs 4g..4g+3.
    // Lanes are consecutive in s -> each load instr covers 256 contiguous bytes;
    // per (row,tile) segment is now 608 B (was 304 B).
    float v[NB1][4];
    #pragma unroll
    for (int i = 0; i < NB1; ++i) {
        int u  = tid + i * NTHREADS;
        int uc = (u < UNITS1) ? u : 0;       // clamp tail to safe in-bounds unit
        int g  = uc / TILE_S;
        int s  = uc - g * TILE_S;
        const float* p = inb + s;
        #pragma unroll
        for (int q = 0; q < 4; ++q) {
            int k = 4 * g + q;
            if (k > ATTR - 1) k = ATTR - 1;  // g==21 quad clamps to attrib 84
            v[i][q] = p[(size_t)k * S_TOT];
        }
    }

    // ---------- Phase 1b: math + LDS scatter (conflict-free) ----------
    // Write 4 consecutive words at lds[s*85 + 4g + q]: lane stride = 85 words
    // (odd) -> 21*l mod 32 covers all 32 banks -> 2-way aliasing = free.
    // (Old mapping had lane stride 340 = 0 mod 4 -> inherent 8-way conflict.)
    #pragma unroll
    for (int i = 0; i < NB1; ++i) {
        int u = tid + i * NTHREADS;
        if (u >= UNITS1) break;              // only trims the last batch slice
        int g = u / TILE_S;
        int s = u - g * TILE_S;

        float r[4];
        if (g != 0) {
            // conf + class scores: plain sigmoid (21/22 of units, convergent)
            #pragma unroll
            for (int q = 0; q < 4; ++q) r[q] = fast_sigmoid(v[i][q]);
        } else {
            // attribs 0..3 = tx,ty,tw,th for spatial position sp
            int sp = s0 + s;                 // global spatial index = h*76 + w
            int hy = sp / WW_;
            int wx = sp - hy * WW_;
            r[0] = ((float)wx + fast_sigmoid(v[i][0])) * (1.0f / 76.0f);
            r[1] = ((float)hy + fast_sigmoid(v[i][1])) * (1.0f / 76.0f);
            r[2] = __builtin_amdgcn_exp2f(v[i][2] * LOG2E) * cw;
            r[3] = __builtin_amdgcn_exp2f(v[i][3] * LOG2E) * ch;
        }

        float* lp = &lds[s * ATTR + 4 * g];
        #pragma unroll
        for (int q = 0; q < 4; ++q) {
            if (4 * g + q < ATTR) lp[q] = r[q];   // drops the 3 pad lanes of g==21
        }
    }

    __syncthreads();

    // ---------- Phase 2: contiguous LDS -> global, batched b128 reads + NT stores
    // out tile base elem = (BA*5776 + s0)*85 ; divisible by 4 -> 16B aligned
    float4v* outv = (float4v*)(out + ((size_t)BA * S_TOT + s0) * ATTR);
    const float4v* ldsv = (const float4v*)lds;

    float4v w[NB2];
    #pragma unroll
    for (int i = 0; i < NB2; ++i) {
        int u  = tid + i * NTHREADS;
        int uc = (u < UNITS2) ? u : 0;
        w[i] = ldsv[uc];
    }
    #pragma unroll
    for (int i = 0; i < NB2; ++i) {
        int u = tid + i * NTHREADS;
        if (u >= UNITS2) break;
        __builtin_nontemporal_store(w[i], &outv[u]);  // write-once stream, keep L2 clean
    }
}

extern "C" void kernel_launch(void* const* d_in, const int* in_sizes, int n_in,
                              void* d_out, int out_size, void* d_ws, size_t ws_size,
                              hipStream_t stream) {
    const float* in = (const float*)d_in[0];   // fp32 input
    float* out = (float*)d_out;                // fp32 output

    dim3 grid(TILES, NB * NA);   // (38, 48) = 1824 blocks
    dim3 block(NTHREADS);
    yolo_layer_kernel<<<grid, block, 0, stream>>>(in, out);
}

// Round 3
// 166.324 us; speedup vs baseline: 1.0257x; 1.0139x over previous
//
#include <hip/hip_runtime.h>
#include <stdint.h>

// Problem constants (B=16, A=3, H=W=76, ATTR=5+80=85)
// Input:  fp32, shape (16, 255, 76, 76)   = 23,566,080 floats (94.3 MB)
// Output: fp32, shape (16, 3, 76, 76, 85) = 23,566,080 floats (94.3 MB)
#define NB       16
#define NA       3
#define HH_      76
#define WW_      76
#define S_TOT    (HH_ * WW_)          // 5776 spatial positions
#define ATTR     85
#define TILE_S   76                   // spatial positions per block (1 image row)
#define TILES    (S_TOT / TILE_S)     // 76
#define NTHREADS 512
#define QUADS    22                   // ceil(85/4) attrib quads per spatial pos
#define UNITS1   (QUADS * TILE_S)     // 1672 phase-1 units (one s x 4 attribs)
#define UNITS2   (TILE_S * ATTR / 4)  // 1615 phase-2 float4 granules
#define NB1      4                    // ceil(UNITS1 / NTHREADS)
#define NB2      4                    // ceil(UNITS2 / NTHREADS)
#define LOG2E    1.44269504088896340f

typedef __attribute__((ext_vector_type(4))) float float4v;

__device__ __forceinline__ float fast_sigmoid(float x) {
    // 1 / (1 + e^-x) = rcp(1 + exp2(-x*log2e)); x ~ N(0,1), |x| <= ~6, finite
    float e = __builtin_amdgcn_exp2f(x * (-LOG2E));
    return __builtin_amdgcn_rcpf(1.0f + e);
}

// R3 theory: R0 (24 waves/CU) and R2 (24 waves/CU) both pinned at 59 us despite
// different traffic/conflicts -> latency/concurrency-bound, time ~ 1/waves.
// This version: E = 12.6 output elems/thread -> LDS 25,840 B/block -> 6 blocks/CU
// by LDS, 4 blocks/CU by the 32-wave cap => 32 waves/CU (up from 24).
// __launch_bounds__(512, 8) pins the register allocator to 8 waves/SIMD.
__global__ __launch_bounds__(NTHREADS, 8)
void yolo_layer_kernel(const float* __restrict__ in,
                       float* __restrict__ out) {
    // LDS holds the fp32 output tile verbatim: [TILE_S][ATTR], unpadded.
    __shared__ __attribute__((aligned(16))) float lds[TILE_S * ATTR]; // 25,840 B

    const int tid  = threadIdx.x;
    const int tile = blockIdx.x;          // 0..75  (spatial tile = one image row)
    const int BA   = blockIdx.y;          // 0..47  (b*3 + a)
    const int a    = BA % NA;
    const int s0   = tile * TILE_S;

    // anchor constants (faithful to reference's off-by-one anchor_h indexing:
    // ANCHOR_W = [10,13,16], ANCHOR_H = [13,16,30])
    const float aw = (a == 0) ? 10.0f : (a == 1) ? 13.0f : 16.0f;
    const float ah = (a == 0) ? 13.0f : (a == 1) ? 16.0f : 30.0f;
    const float cw = aw * (1.0f / 608.0f);
    const float ch = ah * (1.0f / 608.0f);

    const float* inb = in + (size_t)BA * (ATTR * S_TOT) + s0;

    // ---------- Phase 1a: issue ALL loads back-to-back (16 b32 loads/thread) ----
    // Unit u = g*TILE_S + s : one spatial position s, attribs 4g..4g+3.
    // Lanes are consecutive in s -> each load instr covers 256 contiguous bytes.
    // 16 staged floats + addresses fit the VGPR budget -> all 16 stay in flight.
    float v[NB1][4];
    #pragma unroll
    for (int i = 0; i < NB1; ++i) {
        int u  = tid + i * NTHREADS;
        int uc = (u < UNITS1) ? u : 0;       // clamp tail to safe in-bounds unit
        int g  = uc / TILE_S;
        int s  = uc - g * TILE_S;
        const float* p = inb + s;
        #pragma unroll
        for (int q = 0; q < 4; ++q) {
            int k = 4 * g + q;
            if (k > ATTR - 1) k = ATTR - 1;  // g==21 quad clamps to attrib 84 (same line, L1 hit)
            v[i][q] = p[(size_t)k * S_TOT];
        }
    }

    // ---------- Phase 1b: math + LDS scatter (conflict-free) ----------
    // Write 4 consecutive words at lds[s*85 + 4g + q]: lane stride = 85 words
    // (odd) -> all 32 banks covered, 2 lanes/bank = free aliasing.
    #pragma unroll
    for (int i = 0; i < NB1; ++i) {
        int u = tid + i * NTHREADS;
        if (u >= UNITS1) break;              // only trims the last batch slice
        int g = u / TILE_S;
        int s = u - g * TILE_S;

        float r[4];
        if (g != 0) {
            // conf + class scores: plain sigmoid (21/22 of units, convergent)
            #pragma unroll
            for (int q = 0; q < 4; ++q) r[q] = fast_sigmoid(v[i][q]);
        } else {
            // attribs 0..3 = tx,ty,tw,th for spatial position sp
            int sp = s0 + s;                 // global spatial index = h*76 + w
            int hy = sp / WW_;
            int wx = sp - hy * WW_;
            r[0] = ((float)wx + fast_sigmoid(v[i][0])) * (1.0f / 76.0f);
            r[1] = ((float)hy + fast_sigmoid(v[i][1])) * (1.0f / 76.0f);
            r[2] = __builtin_amdgcn_exp2f(v[i][2] * LOG2E) * cw;
            r[3] = __builtin_amdgcn_exp2f(v[i][3] * LOG2E) * ch;
        }

        float* lp = &lds[s * ATTR + 4 * g];
        #pragma unroll
        for (int q = 0; q < 4; ++q) {
            if (4 * g + q < ATTR) lp[q] = r[q];   // drops the 3 pad lanes of g==21
        }
    }

    __syncthreads();

    // ---------- Phase 2: contiguous LDS -> global, batched b128 reads + NT stores
    // out tile base elem = (BA*5776 + s0)*85 ; divisible by 4 -> 16B aligned
    float4v* outv = (float4v*)(out + ((size_t)BA * S_TOT + s0) * ATTR);
    const float4v* ldsv = (const float4v*)lds;

    float4v w[NB2];
    #pragma unroll
    for (int i = 0; i < NB2; ++i) {
        int u  = tid + i * NTHREADS;
        int uc = (u < UNITS2) ? u : 0;
        w[i] = ldsv[uc];
    }
    #pragma unroll
    for (int i = 0; i < NB2; ++i) {
        int u = tid + i * NTHREADS;
        if (u >= UNITS2) break;
        __builtin_nontemporal_store(w[i], &outv[u]);  // write-once stream, keep L2 clean
    }
}

extern "C" void kernel_launch(void* const* d_in, const int* in_sizes, int n_in,
                              void* d_out, int out_size, void* d_ws, size_t ws_size,
                              hipStream_t stream) {
    const float* in = (const float*)d_in[0];   // fp32 input
    float* out = (float*)d_out;                // fp32 output

    dim3 grid(TILES, NB * NA);   // (76, 48) = 3648 blocks
    dim3 block(NTHREADS);
    yolo_layer_kernel<<<grid, block, 0, stream>>>(in, out);
}